// Round 9
// baseline (400.290 us; speedup 1.0000x reference)
//
#include <hip/hip_runtime.h>
#include <hip/hip_bf16.h>
#include <stdint.h>

#define B_   128
#define C_   3
#define H_   64
#define W_   64
#define KS   5
#define OC   64
#define OH   32
#define OW   32
#define PSZ  75          // C*K*K
#define FCIN 65536       // OC*OH*OW
#define HID  1536
#define NCLS 10
#define EPSV 1e-5f

typedef __attribute__((ext_vector_type(8))) short  bf16x8;
typedef __attribute__((ext_vector_type(8))) short  short8;
typedef __attribute__((ext_vector_type(4))) float  f32x4;

static __device__ __forceinline__ float bf2f(short u) {
  union { unsigned int i; float f; } v;
  v.i = ((unsigned int)(unsigned short)u) << 16;
  return v.f;
}
static __device__ __forceinline__ short f2bf(float f) {
  union { float f; unsigned int i; } v; v.f = f;
  unsigned int r = v.i + 0x7FFF + ((v.i >> 16) & 1);   // RNE
  return (short)(r >> 16);
}
static __device__ __forceinline__ float u2f(unsigned int u) {
  union { unsigned int i; float f; } v; v.i = u; return v.f;
}

// async global->LDS, 16B per lane; LDS dest is WAVE-UNIFORM base (+lane*16 by
// HW); the GLOBAL source is per-lane (supports arbitrary scatter).
static __device__ __forceinline__ void gld16(const unsigned short* g, unsigned short* l) {
  __builtin_amdgcn_global_load_lds(
      (const __attribute__((address_space(1))) unsigned int*)g,
      (__attribute__((address_space(3))) unsigned int*)l, 16, 0, 0);
}
static __device__ __forceinline__ void gld16f(const float* g, float* l) {
  __builtin_amdgcn_global_load_lds(
      (const __attribute__((address_space(1))) unsigned int*)g,
      (__attribute__((address_space(3))) unsigned int*)l, 16, 0, 0);
}

// ---------------- K1: LocallyConnected2d conv -> bf16 out [b][o][h*32+w] ----
// grid (32 h, 4 og, 4 zb), block 256 = 32 w * 8 ot, 2 oc/thread.
// xs staged in BF16; taps for output w are STORED cols 2w..2w+4 (storage
// already folds the pad shift: stored col = gcol+2), i.e. uints w, w+1, w+2.
// Weights loaded in c-chunks of 25 (wr2[2][25]=50 VGPR, no spill).
__global__ __launch_bounds__(256, 2) void k1_conv(
    const float* __restrict__ x, const float* __restrict__ lcw,
    unsigned short* __restrict__ outb) {
  const int h  = blockIdx.x;
  const int og = blockIdx.y;
  const int zb = blockIdx.z;
  const int tid = threadIdx.x;
  const int w  = tid & 31;
  const int ot = tid >> 5;
  const int o0 = og * 16 + ot * 2;

  __shared__ unsigned short xs[16][C_][KS][72];  // bf16; gcol stored at col+2

  const int row0 = 2 * h - 2;
  for (int g = 0; g < 2; ++g) {
    const int bg = zb * 2 + g;
    if (g) __syncthreads();

    // zero borders: stored cols {0,1} and {66..71}
    if (tid < 240) {
      int t = tid;
      int r = t % KS;  t /= KS;
      int c = t % C_;
      int b = t / C_;
      *(unsigned int*)&xs[b][c][r][0]  = 0u;
      *(unsigned int*)&xs[b][c][r][66] = 0u;
      *(unsigned int*)&xs[b][c][r][68] = 0u;
      *(unsigned int*)&xs[b][c][r][70] = 0u;
    }
    // interior: 3840 float4 loads -> 2x b32 bf16-pair writes
    for (int v = tid; v < 16 * C_ * KS * 16; v += 256) {
      int col4 = v & 15;
      int t    = v >> 4;
      int r    = t % KS;  t /= KS;
      int c    = t % C_;
      int b    = t / C_;
      int grow = row0 + r;
      f32x4 val = (f32x4){0.f, 0.f, 0.f, 0.f};
      if ((unsigned)grow < 64u)
        val = *(const f32x4*)&x[(((long)(bg * 16 + b) * C_ + c) * 64 + grow) * 64 + col4 * 4];
      unsigned int p0 = ((unsigned int)(unsigned short)f2bf(val[0])) |
                        (((unsigned int)(unsigned short)f2bf(val[1])) << 16);
      unsigned int p1 = ((unsigned int)(unsigned short)f2bf(val[2])) |
                        (((unsigned int)(unsigned short)f2bf(val[3])) << 16);
      *(unsigned int*)&xs[b][c][r][2 + col4 * 4]     = p0;
      *(unsigned int*)&xs[b][c][r][2 + col4 * 4 + 2] = p1;
    }
    __syncthreads();

    float acc[2][16];
    #pragma unroll
    for (int oo = 0; oo < 2; ++oo)
      #pragma unroll
      for (int b = 0; b < 16; ++b) acc[oo][b] = 0.f;

    for (int c = 0; c < C_; ++c) {
      float wr2[2][25];
      {
        const float* wpA = lcw + ((long)o0 * PSZ + c * 25) * 1024 + h * 32 + w;
        const float* wpB = lcw + ((long)(o0 + 1) * PSZ + c * 25) * 1024 + h * 32 + w;
        #pragma unroll
        for (int p = 0; p < 25; ++p) {
          wr2[0][p] = wpA[(long)p * 1024];
          wr2[1][p] = wpB[(long)p * 1024];
        }
      }
      #pragma unroll
      for (int kh = 0; kh < KS; ++kh) {
        #pragma unroll
        for (int b = 0; b < 16; ++b) {
          const unsigned int* rowp = (const unsigned int*)&xs[b][c][kh][0];
          unsigned int d0 = rowp[w];       // stored cols 2w,2w+1   (kw 0,1)
          unsigned int d1 = rowp[w + 1];   // stored cols 2w+2,2w+3 (kw 2,3)
          unsigned int d2 = rowp[w + 2];   // stored col  2w+4      (kw 4)
          float v0 = u2f(d0 << 16), v1 = u2f(d0 & 0xffff0000u);
          float v2 = u2f(d1 << 16), v3 = u2f(d1 & 0xffff0000u);
          float v4 = u2f(d2 << 16);
          const int pb = kh * 5;
          acc[0][b] += wr2[0][pb] * v0 + wr2[0][pb + 1] * v1 + wr2[0][pb + 2] * v2
                     + wr2[0][pb + 3] * v3 + wr2[0][pb + 4] * v4;
          acc[1][b] += wr2[1][pb] * v0 + wr2[1][pb + 1] * v1 + wr2[1][pb + 2] * v2
                     + wr2[1][pb + 3] * v3 + wr2[1][pb + 4] * v4;
        }
      }
    }

    #pragma unroll
    for (int oo = 0; oo < 2; ++oo)
      #pragma unroll
      for (int b = 0; b < 16; ++b)
        outb[((long)(bg * 16 + b) * OC + (o0 + oo)) * 1024 + h * 32 + w] =
            (unsigned short)f2bf(acc[oo][b]);
  }
}

// ---------------- K2: BN1 batch stats -> scale/shift per channel ------------
__global__ __launch_bounds__(1024) void k2_stats(
    const unsigned short* __restrict__ outb,
    const float* __restrict__ g, const float* __restrict__ bta,
    float* __restrict__ sc, float* __restrict__ sh) {
  const int o = blockIdx.x;
  const int tid = threadIdx.x;
  float s = 0.f, s2 = 0.f;
  const int i8 = (tid & 127) * 8;
  const int bsub = tid >> 7;
  for (int pass = 0; pass < 16; ++pass) {
    int b = bsub + pass * 8;
    const short8 v = *(const short8*)(outb + (((long)b * OC + o) << 10) + i8);
    #pragma unroll
    for (int j = 0; j < 8; ++j) { float f = bf2f(v[j]); s += f; s2 += f * f; }
  }
  #pragma unroll
  for (int off = 32; off; off >>= 1) {
    s  += __shfl_down(s, off);
    s2 += __shfl_down(s2, off);
  }
  __shared__ float ls[16], ls2[16];
  int wid = tid >> 6;
  if ((tid & 63) == 0) { ls[wid] = s; ls2[wid] = s2; }
  __syncthreads();
  if (tid == 0) {
    float ts = 0.f, ts2 = 0.f;
    for (int i = 0; i < 16; ++i) { ts += ls[i]; ts2 += ls2[i]; }
    const float inv = 1.0f / (float)(B_ * 1024);
    float mean = ts * inv;
    float var  = ts2 * inv - mean * mean;
    float rstd = 1.0f / sqrtf(var + EPSV);
    float scv  = g[o] * rstd;
    sc[o] = scv;
    sh[o] = bta[o] - mean * scv;
  }
}

// ---------------- K2.5: BN1+ReLU -> SWIZZLED packed bf16 activations --------
// Chunk layout (16B units): chunk c = kb*512 + mf*64 + lq*16 + l15
//   holds A[m = mf*16+l15][k = kb*32 + lq*8 .. +7]
__global__ __launch_bounds__(256) void k25_pack(
    const unsigned short* __restrict__ outb,
    const float* __restrict__ sc, const float* __restrict__ sh,
    unsigned short* __restrict__ ab) {
  const int c = blockIdx.x * 256 + threadIdx.x;   // chunk id, 2048*512 total
  const int l15 = c & 15;
  const int lq  = (c >> 4) & 3;
  const int mf  = (c >> 6) & 7;
  const int kb  = c >> 9;
  const int m   = mf * 16 + l15;
  const int k   = kb * 32 + lq * 8;
  const int o   = k >> 10;
  const int hw  = k & 1023;
  float scv = sc[o], shv = sh[o];
  short8 v = *(const short8*)(outb + ((long)m * 64 + o) * 1024 + hw);
  short8 r;
  #pragma unroll
  for (int j = 0; j < 8; ++j) {
    float f = bf2f(v[j]) * scv + shv;
    r[j] = f2bf(fmaxf(f, 0.f));
  }
  *(short8*)(ab + (long)c * 8) = r;
}

// ---------------- K3: FC1 GEMM — counted-vmcnt depth-4 DMA pipeline ---------
// 5 LDS buffers (80KB, 2 blocks/CU). Per step: {vmcnt(12) [drain stage(t),
// keep t+1..t+3 in flight ACROSS the barrier] -> barrier -> STAGE(t+4) ->
// COMPUTE(t)}. Issue-to-consume distance = 4 steps (covers HBM ~900cyc).
// + per-block k-phase rotation (channel spread) + XCD swizzle + setprio.
__global__ __launch_bounds__(256, 2) void k3_gemm(
    const unsigned short* __restrict__ ab, const float* __restrict__ w1,
    float* __restrict__ part, int ksteps, int splits) {
  const int nwg = 24 * splits;
  const int chunk = nwg >> 3;                 // nwg % 8 == 0
  const int bid = blockIdx.x;
  const int lid = (bid & 7) * chunk + (bid >> 3);
  const int split = lid / 24;
  const int ntile = lid % 24;

  const int tid  = threadIdx.x;
  const int lane = tid & 63;
  const int wid  = tid >> 6;
  const int n0   = ntile * 64 + wid * 16;
  const int l15  = lane & 15;
  const int lq   = lane >> 4;

  __shared__ unsigned short sa[5][4096];   // A: 5 x 8KB
  __shared__ float sw[5][4][512];          // W: 5 x 8KB

  const int kb0 = split * ksteps;
  const int kmask = ksteps - 1;               // ksteps is pow2
  const int phase = (lid * 29) & kmask;       // per-block k-rotation
  const long wsrc = (long)(n0 + l15) * FCIN + (long)kb0 * 32 + lq * 8;
  const int last = ksteps - 1;

#define STAGE(T, BUF) do {                                                   \
    int Tp = ((T) + phase) & kmask;                                          \
    long gb = ((long)(kb0 + Tp) * 512 + wid * 128) * 8;                      \
    unsigned short* lb = &sa[BUF][wid * 1024];                               \
    gld16(ab + gb + (long)lane * 8, lb);                                     \
    gld16(ab + gb + 512 + (long)lane * 8, lb + 512);                         \
    const float* wg = w1 + wsrc + (long)Tp * 32;                             \
    float* wlb = &sw[BUF][wid][0];                                           \
    gld16f(wg, wlb);                                                         \
    gld16f(wg + 4, wlb + 256);                                               \
  } while (0)

#define COMPUTE(X) do {                                                      \
    f32x4 wv0 = *(const f32x4*)&sw[X][wid][lane * 4];                        \
    f32x4 wv1 = *(const f32x4*)&sw[X][wid][256 + lane * 4];                  \
    bf16x8 bfr;                                                              \
    _Pragma("unroll")                                                        \
    for (int j = 0; j < 4; ++j) bfr[j] = f2bf(wv0[j]);                       \
    _Pragma("unroll")                                                        \
    for (int j = 0; j < 4; ++j) bfr[4 + j] = f2bf(wv1[j]);                   \
    __builtin_amdgcn_s_setprio(1);                                           \
    _Pragma("unroll")                                                        \
    for (int m = 0; m < 8; ++m) {                                            \
      bf16x8 afr = *(const bf16x8*)(&sa[X][m * 512 + lane * 8]);             \
      acc[m] = __builtin_amdgcn_mfma_f32_16x16x32_bf16(afr, bfr, acc[m], 0, 0, 0); \
    }                                                                        \
    __builtin_amdgcn_s_setprio(0);                                           \
  } while (0)

  f32x4 acc[8];
  #pragma unroll
  for (int m = 0; m < 8; ++m) acc[m] = (f32x4){0.f, 0.f, 0.f, 0.f};

  STAGE(0, 0);
  STAGE(1, 1);
  STAGE(2, 2);
  STAGE(3, 3);

  for (int t = 0; t < ksteps; ++t) {
    asm volatile("s_waitcnt vmcnt(12)" ::: "memory");  // stage(t) landed; t+1..t+3 in flight
    __builtin_amdgcn_sched_barrier(0);
    __builtin_amdgcn_s_barrier();
    __builtin_amdgcn_sched_barrier(0);
    int tn = (t + 4 <= last) ? (t + 4) : last;         // clamped dummy keeps DMA count uniform
    STAGE(tn, (t + 4) % 5);
    COMPUTE(t % 5);
  }
  asm volatile("s_waitcnt vmcnt(0)" ::: "memory");
#undef STAGE
#undef COMPUTE

  float* pp = part + (long)split * (B_ * HID);
  #pragma unroll
  for (int m = 0; m < 8; ++m) {
    int row = m * 16 + lq * 4;
    #pragma unroll
    for (int r = 0; r < 4; ++r)
      pp[(long)(row + r) * HID + n0 + l15] = acc[m][r];
  }
}

// ---------------- K4: reduce split-K + BN2 + ReLU -> h2 fp32 ----------------
__global__ __launch_bounds__(256) void k4_bn2(
    const float* __restrict__ part, const float* __restrict__ g2,
    const float* __restrict__ b2, float* __restrict__ h2, int splits) {
  const int nb = blockIdx.x;
  const int tid = threadIdx.x;
  const int nl = tid & 3;
  const int bt = tid >> 2;          // 0..63
  const int n  = nb * 4 + nl;

  float h0 = 0.f, h1 = 0.f;
  for (int s = 0; s < splits; ++s) {
    const float* pp = part + (long)s * (B_ * HID) + n;
    h0 += pp[(long)bt * HID];
    h1 += pp[(long)(bt + 64) * HID];
  }
  float s1 = h0 + h1, s2v = h0 * h0 + h1 * h1;

  __shared__ float r1[256], r2[256];
  r1[tid] = s1; r2[tid] = s2v;
  __syncthreads();
  for (int off = 32; off; off >>= 1) {
    if (bt < off) { r1[tid] += r1[tid + off * 4]; r2[tid] += r2[tid + off * 4]; }
    __syncthreads();
  }
  __shared__ float scs[4], shs[4];
  if (bt == 0) {
    float mean = r1[nl] * (1.0f / 128.f);
    float var  = r2[nl] * (1.0f / 128.f) - mean * mean;
    float rstd = 1.0f / sqrtf(var + EPSV);
    float sc = g2[n] * rstd;
    scs[nl] = sc; shs[nl] = b2[n] - mean * sc;
  }
  __syncthreads();
  float sc = scs[nl], shf = shs[nl];
  h2[(long)bt * HID + n]        = fmaxf(h0 * sc + shf, 0.f);
  h2[(long)(bt + 64) * HID + n] = fmaxf(h1 * sc + shf, 0.f);
}

// ---------------- K5: FC2 -> out [128,10] -----------------------------------
__global__ __launch_bounds__(256) void k5_fc2(
    const float* __restrict__ h2, const float* __restrict__ w2,
    float* __restrict__ out) {
  const int b = blockIdx.x;
  const int tid = threadIdx.x;
  float acc[NCLS];
  #pragma unroll
  for (int c = 0; c < NCLS; ++c) acc[c] = 0.f;
  for (int n = tid; n < HID; n += 256) {
    float hvv = h2[(long)b * HID + n];
    #pragma unroll
    for (int c = 0; c < NCLS; ++c) acc[c] += hvv * w2[c * HID + n];
  }
  #pragma unroll
  for (int off = 32; off; off >>= 1)
    #pragma unroll
    for (int c = 0; c < NCLS; ++c) acc[c] += __shfl_down(acc[c], off);
  __shared__ float ls[4][NCLS];
  int wid = tid >> 6;
  if ((tid & 63) == 0)
    for (int c = 0; c < NCLS; ++c) ls[wid][c] = acc[c];
  __syncthreads();
  if (tid < NCLS)
    out[b * NCLS + tid] = ls[0][tid] + ls[1][tid] + ls[2][tid] + ls[3][tid];
}

extern "C" void kernel_launch(void* const* d_in, const int* in_sizes, int n_in,
                              void* d_out, int out_size, void* d_ws, size_t ws_size,
                              hipStream_t stream) {
  const float* x    = (const float*)d_in[0];
  const float* lcw  = (const float*)d_in[1];
  const float* bn1g = (const float*)d_in[2];
  const float* bn1b = (const float*)d_in[3];
  const float* fc1w = (const float*)d_in[4];
  const float* bn2g = (const float*)d_in[5];
  const float* bn2b = (const float*)d_in[6];
  const float* fc2w = (const float*)d_in[7];
  float* out = (float*)d_out;

  char* ws = (char*)d_ws;
  unsigned short* outb = (unsigned short*)(ws);                              // 16 MiB
  unsigned short* ab   = (unsigned short*)(ws + (size_t)16 * 1024 * 1024);   // 16 MiB
  float* sc1 = (float*)(ws + (size_t)32 * 1024 * 1024);
  float* sh1 = sc1 + 64;
  size_t base = (size_t)32 * 1024 * 1024 + 4096;
  float* part = (float*)(ws + base);

  int splits = 32;                       // auto-degrade if ws too small
  size_t h2need = (size_t)B_ * HID * 4;
  while (splits > 4 && base + (size_t)splits * B_ * HID * 4 + h2need > ws_size)
    splits >>= 1;
  float* h2 = (float*)(ws + base + (size_t)splits * B_ * HID * 4);

  k1_conv<<<dim3(32, 4, 4), 256, 0, stream>>>(x, lcw, outb);
  k2_stats<<<64, 1024, 0, stream>>>(outb, bn1g, bn1b, sc1, sh1);
  k25_pack<<<4096, 256, 0, stream>>>(outb, sc1, sh1, ab);
  int ksteps = FCIN / splits / 32;
  k3_gemm<<<24 * splits, 256, 0, stream>>>(ab, fc1w, part, ksteps, splits);
  k4_bn2<<<384, 256, 0, stream>>>(part, bn2g, bn2b, h2, splits);
  k5_fc2<<<128, 256, 0, stream>>>(h2, fc2w, out);
}

// Round 10
// 374.242 us; speedup vs baseline: 1.0696x; 1.0696x over previous
//
#include <hip/hip_runtime.h>
#include <hip/hip_bf16.h>
#include <stdint.h>

#define B_   128
#define C_   3
#define H_   64
#define W_   64
#define KS   5
#define OC   64
#define OH   32
#define OW   32
#define PSZ  75          // C*K*K
#define FCIN 65536       // OC*OH*OW
#define HID  1536
#define NCLS 10
#define EPSV 1e-5f

typedef __attribute__((ext_vector_type(8))) short  bf16x8;
typedef __attribute__((ext_vector_type(8))) short  short8;
typedef __attribute__((ext_vector_type(4))) float  f32x4;

static __device__ __forceinline__ float bf2f(short u) {
  union { unsigned int i; float f; } v;
  v.i = ((unsigned int)(unsigned short)u) << 16;
  return v.f;
}
static __device__ __forceinline__ short f2bf(float f) {
  union { float f; unsigned int i; } v; v.f = f;
  unsigned int r = v.i + 0x7FFF + ((v.i >> 16) & 1);   // RNE
  return (short)(r >> 16);
}
static __device__ __forceinline__ float u2f(unsigned int u) {
  union { unsigned int i; float f; } v; v.i = u; return v.f;
}

// async global->LDS, 16B per lane; LDS dest is WAVE-UNIFORM base (+lane*16 by
// HW); the GLOBAL source is per-lane (supports arbitrary scatter).
static __device__ __forceinline__ void gld16(const unsigned short* g, unsigned short* l) {
  __builtin_amdgcn_global_load_lds(
      (const __attribute__((address_space(1))) unsigned int*)g,
      (__attribute__((address_space(3))) unsigned int*)l, 16, 0, 0);
}
static __device__ __forceinline__ void gld16f(const float* g, float* l) {
  __builtin_amdgcn_global_load_lds(
      (const __attribute__((address_space(1))) unsigned int*)g,
      (__attribute__((address_space(3))) unsigned int*)l, 16, 0, 0);
}

// ---------------- K1: LocallyConnected2d conv -> bf16 out [b][o][h*32+w] ----
// grid (32 h, 4 og, 4 zb), block 256 = 32 w * 8 ot, 2 oc/thread.
// xs in BF16 (taps = stored uints w, w+1, w+2). Weights in c-chunks of 25
// (wr2[2][25] = 50 VGPR); #pragma unroll 1 on the c-loop is ESSENTIAL:
// full unroll makes all 150 weight regs live -> spill past the 128 cap
// (R9: VGPR=128, 367MB scratch writes, 0.5% occupancy, 260us).
__global__ __launch_bounds__(256, 2) void k1_conv(
    const float* __restrict__ x, const float* __restrict__ lcw,
    unsigned short* __restrict__ outb) {
  const int h  = blockIdx.x;
  const int og = blockIdx.y;
  const int zb = blockIdx.z;
  const int tid = threadIdx.x;
  const int w  = tid & 31;
  const int ot = tid >> 5;
  const int o0 = og * 16 + ot * 2;

  __shared__ unsigned short xs[16][C_][KS][72];  // bf16; gcol stored at col+2

  const int row0 = 2 * h - 2;
  for (int g = 0; g < 2; ++g) {
    const int bg = zb * 2 + g;
    if (g) __syncthreads();

    // zero borders: stored cols {0,1} and {66..71}
    if (tid < 240) {
      int t = tid;
      int r = t % KS;  t /= KS;
      int c = t % C_;
      int b = t / C_;
      *(unsigned int*)&xs[b][c][r][0]  = 0u;
      *(unsigned int*)&xs[b][c][r][66] = 0u;
      *(unsigned int*)&xs[b][c][r][68] = 0u;
      *(unsigned int*)&xs[b][c][r][70] = 0u;
    }
    // interior: 3840 float4 loads -> 2x b32 bf16-pair writes
    for (int v = tid; v < 16 * C_ * KS * 16; v += 256) {
      int col4 = v & 15;
      int t    = v >> 4;
      int r    = t % KS;  t /= KS;
      int c    = t % C_;
      int b    = t / C_;
      int grow = row0 + r;
      f32x4 val = (f32x4){0.f, 0.f, 0.f, 0.f};
      if ((unsigned)grow < 64u)
        val = *(const f32x4*)&x[(((long)(bg * 16 + b) * C_ + c) * 64 + grow) * 64 + col4 * 4];
      unsigned int p0 = ((unsigned int)(unsigned short)f2bf(val[0])) |
                        (((unsigned int)(unsigned short)f2bf(val[1])) << 16);
      unsigned int p1 = ((unsigned int)(unsigned short)f2bf(val[2])) |
                        (((unsigned int)(unsigned short)f2bf(val[3])) << 16);
      *(unsigned int*)&xs[b][c][r][2 + col4 * 4]     = p0;
      *(unsigned int*)&xs[b][c][r][2 + col4 * 4 + 2] = p1;
    }
    __syncthreads();

    float acc[2][16];
    #pragma unroll
    for (int oo = 0; oo < 2; ++oo)
      #pragma unroll
      for (int b = 0; b < 16; ++b) acc[oo][b] = 0.f;

    #pragma unroll 1
    for (int c = 0; c < C_; ++c) {
      float wr2[2][25];
      {
        const float* wpA = lcw + ((long)o0 * PSZ + c * 25) * 1024 + h * 32 + w;
        const float* wpB = lcw + ((long)(o0 + 1) * PSZ + c * 25) * 1024 + h * 32 + w;
        #pragma unroll
        for (int p = 0; p < 25; ++p) {
          wr2[0][p] = wpA[(long)p * 1024];
          wr2[1][p] = wpB[(long)p * 1024];
        }
      }
      #pragma unroll
      for (int kh = 0; kh < KS; ++kh) {
        #pragma unroll
        for (int b = 0; b < 16; ++b) {
          const unsigned int* rowp = (const unsigned int*)&xs[b][c][kh][0];
          unsigned int d0 = rowp[w];       // stored cols 2w,2w+1   (kw 0,1)
          unsigned int d1 = rowp[w + 1];   // stored cols 2w+2,2w+3 (kw 2,3)
          unsigned int d2 = rowp[w + 2];   // stored col  2w+4      (kw 4)
          float v0 = u2f(d0 << 16), v1 = u2f(d0 & 0xffff0000u);
          float v2 = u2f(d1 << 16), v3 = u2f(d1 & 0xffff0000u);
          float v4 = u2f(d2 << 16);
          const int pb = kh * 5;
          acc[0][b] += wr2[0][pb] * v0 + wr2[0][pb + 1] * v1 + wr2[0][pb + 2] * v2
                     + wr2[0][pb + 3] * v3 + wr2[0][pb + 4] * v4;
          acc[1][b] += wr2[1][pb] * v0 + wr2[1][pb + 1] * v1 + wr2[1][pb + 2] * v2
                     + wr2[1][pb + 3] * v3 + wr2[1][pb + 4] * v4;
        }
      }
    }

    #pragma unroll
    for (int oo = 0; oo < 2; ++oo)
      #pragma unroll
      for (int b = 0; b < 16; ++b)
        outb[((long)(bg * 16 + b) * OC + (o0 + oo)) * 1024 + h * 32 + w] =
            (unsigned short)f2bf(acc[oo][b]);
  }
}

// ---------------- K2: BN1 batch stats -> scale/shift per channel ------------
__global__ __launch_bounds__(1024) void k2_stats(
    const unsigned short* __restrict__ outb,
    const float* __restrict__ g, const float* __restrict__ bta,
    float* __restrict__ sc, float* __restrict__ sh) {
  const int o = blockIdx.x;
  const int tid = threadIdx.x;
  float s = 0.f, s2 = 0.f;
  const int i8 = (tid & 127) * 8;
  const int bsub = tid >> 7;
  for (int pass = 0; pass < 16; ++pass) {
    int b = bsub + pass * 8;
    const short8 v = *(const short8*)(outb + (((long)b * OC + o) << 10) + i8);
    #pragma unroll
    for (int j = 0; j < 8; ++j) { float f = bf2f(v[j]); s += f; s2 += f * f; }
  }
  #pragma unroll
  for (int off = 32; off; off >>= 1) {
    s  += __shfl_down(s, off);
    s2 += __shfl_down(s2, off);
  }
  __shared__ float ls[16], ls2[16];
  int wid = tid >> 6;
  if ((tid & 63) == 0) { ls[wid] = s; ls2[wid] = s2; }
  __syncthreads();
  if (tid == 0) {
    float ts = 0.f, ts2 = 0.f;
    for (int i = 0; i < 16; ++i) { ts += ls[i]; ts2 += ls2[i]; }
    const float inv = 1.0f / (float)(B_ * 1024);
    float mean = ts * inv;
    float var  = ts2 * inv - mean * mean;
    float rstd = 1.0f / sqrtf(var + EPSV);
    float scv  = g[o] * rstd;
    sc[o] = scv;
    sh[o] = bta[o] - mean * scv;
  }
}

// ---------------- K2.5: BN1+ReLU -> SWIZZLED packed bf16 activations --------
// Chunk layout (16B units): chunk c = kb*512 + mf*64 + lq*16 + l15
//   holds A[m = mf*16+l15][k = kb*32 + lq*8 .. +7]
__global__ __launch_bounds__(256) void k25_pack(
    const unsigned short* __restrict__ outb,
    const float* __restrict__ sc, const float* __restrict__ sh,
    unsigned short* __restrict__ ab) {
  const int c = blockIdx.x * 256 + threadIdx.x;   // chunk id, 2048*512 total
  const int l15 = c & 15;
  const int lq  = (c >> 4) & 3;
  const int mf  = (c >> 6) & 7;
  const int kb  = c >> 9;
  const int m   = mf * 16 + l15;
  const int k   = kb * 32 + lq * 8;
  const int o   = k >> 10;
  const int hw  = k & 1023;
  float scv = sc[o], shv = sh[o];
  short8 v = *(const short8*)(outb + ((long)m * 64 + o) * 1024 + hw);
  short8 r;
  #pragma unroll
  for (int j = 0; j < 8; ++j) {
    float f = bf2f(v[j]) * scv + shv;
    r[j] = f2bf(fmaxf(f, 0.f));
  }
  *(short8*)(ab + (long)c * 8) = r;
}

// ---------------- K3: FC1 GEMM — SUPERSTEP (k=64) DMA pipeline --------------
// Each stage phase issues a full 64-k superstep (2 substeps): per W row 256B
// of CONTIGUOUS addresses issued back-to-back -> one DRAM page activation
// serves 2x the data (R9 analysis: 128B/activation page-thrash capped HBM at
// ~3.5 TB/s). NBUF=2 (64KB LDS, 2 blocks/CU); counted vmcnt(8) keeps the
// next superstep's DMAs in flight across both barriers.
// + per-block superstep-phase rotation (channel spread) + XCD swizzle + setprio.
__global__ __launch_bounds__(256, 2) void k3_gemm(
    const unsigned short* __restrict__ ab, const float* __restrict__ w1,
    float* __restrict__ part, int ksteps, int splits) {
  const int nsup = ksteps >> 1;               // supersteps of 64 k
  const int nwg = 24 * splits;
  const int chunk = nwg >> 3;                 // nwg % 8 == 0
  const int bid = blockIdx.x;
  const int lid = (bid & 7) * chunk + (bid >> 3);
  const int split = lid / 24;
  const int ntile = lid % 24;

  const int tid  = threadIdx.x;
  const int lane = tid & 63;
  const int wid  = tid >> 6;
  const int n0   = ntile * 64 + wid * 16;
  const int l15  = lane & 15;
  const int lq   = lane >> 4;

  __shared__ unsigned short sa[2][2][4096];   // A: 2 buf x 2 sub x 8KB = 32KB
  __shared__ float sw[2][2][4][512];          // W: 2 buf x 2 sub x 8KB = 32KB

  const int kb0 = split * ksteps;
  const int smask = nsup - 1;                 // nsup is pow2
  const int phase = (lid * 29) & smask;       // per-block superstep rotation
  const long wsrc = (long)(n0 + l15) * FCIN + (long)kb0 * 32 + lq * 8;
  const int lastS = nsup - 1;

#define STAGE(S, BUF) do {                                                   \
    int Sp = ((S) + phase) & smask;                                          \
    _Pragma("unroll")                                                        \
    for (int sub = 0; sub < 2; ++sub) {                                      \
      int ks = Sp * 2 + sub;                                                 \
      long gb = ((long)(kb0 + ks) * 512 + wid * 128) * 8;                    \
      unsigned short* lb = &sa[BUF][sub][wid * 1024];                        \
      gld16(ab + gb + (long)lane * 8, lb);                                   \
      gld16(ab + gb + 512 + (long)lane * 8, lb + 512);                       \
      const float* wg = w1 + wsrc + (long)ks * 32;                           \
      float* wlb = &sw[BUF][sub][wid][0];                                    \
      gld16f(wg, wlb);                                                       \
      gld16f(wg + 4, wlb + 256);                                             \
    }                                                                        \
  } while (0)

#define COMPUTE(X, SUB) do {                                                 \
    f32x4 wv0 = *(const f32x4*)&sw[X][SUB][wid][lane * 4];                   \
    f32x4 wv1 = *(const f32x4*)&sw[X][SUB][wid][256 + lane * 4];             \
    bf16x8 bfr;                                                              \
    _Pragma("unroll")                                                        \
    for (int j = 0; j < 4; ++j) bfr[j] = f2bf(wv0[j]);                       \
    _Pragma("unroll")                                                        \
    for (int j = 0; j < 4; ++j) bfr[4 + j] = f2bf(wv1[j]);                   \
    __builtin_amdgcn_s_setprio(1);                                           \
    _Pragma("unroll")                                                        \
    for (int m = 0; m < 8; ++m) {                                            \
      bf16x8 afr = *(const bf16x8*)(&sa[X][SUB][m * 512 + lane * 8]);        \
      acc[m] = __builtin_amdgcn_mfma_f32_16x16x32_bf16(afr, bfr, acc[m], 0, 0, 0); \
    }                                                                        \
    __builtin_amdgcn_s_setprio(0);                                           \
  } while (0)

  f32x4 acc[8];
  #pragma unroll
  for (int m = 0; m < 8; ++m) acc[m] = (f32x4){0.f, 0.f, 0.f, 0.f};

  STAGE(0, 0);

  for (int t = 0; t < nsup; ++t) {
    int tn = (t + 1 <= lastS) ? (t + 1) : lastS;   // clamped dummy: uniform DMA count
    STAGE(tn, (t + 1) & 1);                        // writes other buffer
    asm volatile("s_waitcnt vmcnt(8)" ::: "memory"); // drain stage(t); keep stage(t+1) in flight
    __builtin_amdgcn_sched_barrier(0);
    __builtin_amdgcn_s_barrier();
    __builtin_amdgcn_sched_barrier(0);
    COMPUTE(t & 1, 0);
    COMPUTE(t & 1, 1);
    __builtin_amdgcn_s_barrier();                  // readers done before next STAGE overwrites
  }
  asm volatile("s_waitcnt vmcnt(0)" ::: "memory");
#undef STAGE
#undef COMPUTE

  float* pp = part + (long)split * (B_ * HID);
  #pragma unroll
  for (int m = 0; m < 8; ++m) {
    int row = m * 16 + lq * 4;
    #pragma unroll
    for (int r = 0; r < 4; ++r)
      pp[(long)(row + r) * HID + n0 + l15] = acc[m][r];
  }
}

// ---------------- K4: reduce split-K + BN2 + ReLU -> h2 fp32 ----------------
__global__ __launch_bounds__(256) void k4_bn2(
    const float* __restrict__ part, const float* __restrict__ g2,
    const float* __restrict__ b2, float* __restrict__ h2, int splits) {
  const int nb = blockIdx.x;
  const int tid = threadIdx.x;
  const int nl = tid & 3;
  const int bt = tid >> 2;          // 0..63
  const int n  = nb * 4 + nl;

  float h0 = 0.f, h1 = 0.f;
  for (int s = 0; s < splits; ++s) {
    const float* pp = part + (long)s * (B_ * HID) + n;
    h0 += pp[(long)bt * HID];
    h1 += pp[(long)(bt + 64) * HID];
  }
  float s1 = h0 + h1, s2v = h0 * h0 + h1 * h1;

  __shared__ float r1[256], r2[256];
  r1[tid] = s1; r2[tid] = s2v;
  __syncthreads();
  for (int off = 32; off; off >>= 1) {
    if (bt < off) { r1[tid] += r1[tid + off * 4]; r2[tid] += r2[tid + off * 4]; }
    __syncthreads();
  }
  __shared__ float scs[4], shs[4];
  if (bt == 0) {
    float mean = r1[nl] * (1.0f / 128.f);
    float var  = r2[nl] * (1.0f / 128.f) - mean * mean;
    float rstd = 1.0f / sqrtf(var + EPSV);
    float sc = g2[n] * rstd;
    scs[nl] = sc; shs[nl] = b2[n] - mean * sc;
  }
  __syncthreads();
  float sc = scs[nl], shf = shs[nl];
  h2[(long)bt * HID + n]        = fmaxf(h0 * sc + shf, 0.f);
  h2[(long)(bt + 64) * HID + n] = fmaxf(h1 * sc + shf, 0.f);
}

// ---------------- K5: FC2 -> out [128,10] -----------------------------------
__global__ __launch_bounds__(256) void k5_fc2(
    const float* __restrict__ h2, const float* __restrict__ w2,
    float* __restrict__ out) {
  const int b = blockIdx.x;
  const int tid = threadIdx.x;
  float acc[NCLS];
  #pragma unroll
  for (int c = 0; c < NCLS; ++c) acc[c] = 0.f;
  for (int n = tid; n < HID; n += 256) {
    float hvv = h2[(long)b * HID + n];
    #pragma unroll
    for (int c = 0; c < NCLS; ++c) acc[c] += hvv * w2[c * HID + n];
  }
  #pragma unroll
  for (int off = 32; off; off >>= 1)
    #pragma unroll
    for (int c = 0; c < NCLS; ++c) acc[c] += __shfl_down(acc[c], off);
  __shared__ float ls[4][NCLS];
  int wid = tid >> 6;
  if ((tid & 63) == 0)
    for (int c = 0; c < NCLS; ++c) ls[wid][c] = acc[c];
  __syncthreads();
  if (tid < NCLS)
    out[b * NCLS + tid] = ls[0][tid] + ls[1][tid] + ls[2][tid] + ls[3][tid];
}

extern "C" void kernel_launch(void* const* d_in, const int* in_sizes, int n_in,
                              void* d_out, int out_size, void* d_ws, size_t ws_size,
                              hipStream_t stream) {
  const float* x    = (const float*)d_in[0];
  const float* lcw  = (const float*)d_in[1];
  const float* bn1g = (const float*)d_in[2];
  const float* bn1b = (const float*)d_in[3];
  const float* fc1w = (const float*)d_in[4];
  const float* bn2g = (const float*)d_in[5];
  const float* bn2b = (const float*)d_in[6];
  const float* fc2w = (const float*)d_in[7];
  float* out = (float*)d_out;

  char* ws = (char*)d_ws;
  unsigned short* outb = (unsigned short*)(ws);                              // 16 MiB
  unsigned short* ab   = (unsigned short*)(ws + (size_t)16 * 1024 * 1024);   // 16 MiB
  float* sc1 = (float*)(ws + (size_t)32 * 1024 * 1024);
  float* sh1 = sc1 + 64;
  size_t base = (size_t)32 * 1024 * 1024 + 4096;
  float* part = (float*)(ws + base);

  int splits = 32;                       // auto-degrade if ws too small
  size_t h2need = (size_t)B_ * HID * 4;
  while (splits > 4 && base + (size_t)splits * B_ * HID * 4 + h2need > ws_size)
    splits >>= 1;
  float* h2 = (float*)(ws + base + (size_t)splits * B_ * HID * 4);

  k1_conv<<<dim3(32, 4, 4), 256, 0, stream>>>(x, lcw, outb);
  k2_stats<<<64, 1024, 0, stream>>>(outb, bn1g, bn1b, sc1, sh1);
  k25_pack<<<4096, 256, 0, stream>>>(outb, sc1, sh1, ab);
  int ksteps = FCIN / splits / 32;
  k3_gemm<<<24 * splits, 256, 0, stream>>>(ab, fc1w, part, ksteps, splits);
  k4_bn2<<<384, 256, 0, stream>>>(part, bn2g, bn2b, h2, splits);
  k5_fc2<<<128, 256, 0, stream>>>(h2, fc2w, out);
}

// Round 11
// 209.626 us; speedup vs baseline: 1.9095x; 1.7853x over previous
//
#include <hip/hip_runtime.h>
#include <hip/hip_bf16.h>
#include <stdint.h>

#define B_   128
#define C_   3
#define H_   64
#define W_   64
#define KS   5
#define OC   64
#define OH   32
#define OW   32
#define PSZ  75          // C*K*K
#define FCIN 65536       // OC*OH*OW
#define HID  1536
#define NCLS 10
#define EPSV 1e-5f

typedef __attribute__((ext_vector_type(8))) short  bf16x8;
typedef __attribute__((ext_vector_type(8))) short  short8;
typedef __attribute__((ext_vector_type(4))) float  f32x4;

static __device__ __forceinline__ float bf2f(short u) {
  union { unsigned int i; float f; } v;
  v.i = ((unsigned int)(unsigned short)u) << 16;
  return v.f;
}
static __device__ __forceinline__ short f2bf(float f) {
  union { float f; unsigned int i; } v; v.f = f;
  unsigned int r = v.i + 0x7FFF + ((v.i >> 16) & 1);   // RNE
  return (short)(r >> 16);
}
static __device__ __forceinline__ float u2f(unsigned int u) {
  union { unsigned int i; float f; } v; v.i = u; return v.f;
}

// async global->LDS, 16B per lane; LDS dest is WAVE-UNIFORM base (+lane*16 by
// HW); the GLOBAL source is per-lane (supports arbitrary scatter).
static __device__ __forceinline__ void gld16(const unsigned short* g, unsigned short* l) {
  __builtin_amdgcn_global_load_lds(
      (const __attribute__((address_space(1))) unsigned int*)g,
      (__attribute__((address_space(3))) unsigned int*)l, 16, 0, 0);
}
static __device__ __forceinline__ void gld16f(const float* g, float* l) {
  __builtin_amdgcn_global_load_lds(
      (const __attribute__((address_space(1))) unsigned int*)g,
      (__attribute__((address_space(3))) unsigned int*)l, 16, 0, 0);
}

// ---------------- K1: LocallyConnected2d conv -> bf16 out [b][o][h*32+w] ----
// grid (32 h, 4 og, 4 zb), block 256 = 32 w * 8 ot, 2 oc/thread.
// Weights loaded in KH-CHUNKS of 5 (wA/wB = 10 regs live) -- small enough
// that even compiler look-ahead pipelining of 2-3 chunks cannot spill
// (R9/R10 lesson: 50-reg chunks + look-ahead pinned VGPR at the 128 cap and
// spilled ~370MB to scratch). xs in BF16; taps = stored uints w, w+1, w+2.
__global__ __launch_bounds__(256, 2) void k1_conv(
    const float* __restrict__ x, const float* __restrict__ lcw,
    unsigned short* __restrict__ outb) {
  const int h  = blockIdx.x;
  const int og = blockIdx.y;
  const int zb = blockIdx.z;
  const int tid = threadIdx.x;
  const int w  = tid & 31;
  const int ot = tid >> 5;
  const int o0 = og * 16 + ot * 2;

  __shared__ unsigned short xs[16][C_][KS][72];  // bf16; gcol stored at col+2

  const int row0 = 2 * h - 2;
  for (int g = 0; g < 2; ++g) {
    const int bg = zb * 2 + g;
    if (g) __syncthreads();

    // zero borders: stored cols {0,1} and {66..71}
    if (tid < 240) {
      int t = tid;
      int r = t % KS;  t /= KS;
      int c = t % C_;
      int b = t / C_;
      *(unsigned int*)&xs[b][c][r][0]  = 0u;
      *(unsigned int*)&xs[b][c][r][66] = 0u;
      *(unsigned int*)&xs[b][c][r][68] = 0u;
      *(unsigned int*)&xs[b][c][r][70] = 0u;
    }
    // interior: 3840 float4 loads -> 2x b32 bf16-pair writes
    for (int v = tid; v < 16 * C_ * KS * 16; v += 256) {
      int col4 = v & 15;
      int t    = v >> 4;
      int r    = t % KS;  t /= KS;
      int c    = t % C_;
      int b    = t / C_;
      int grow = row0 + r;
      f32x4 val = (f32x4){0.f, 0.f, 0.f, 0.f};
      if ((unsigned)grow < 64u)
        val = *(const f32x4*)&x[(((long)(bg * 16 + b) * C_ + c) * 64 + grow) * 64 + col4 * 4];
      unsigned int p0 = ((unsigned int)(unsigned short)f2bf(val[0])) |
                        (((unsigned int)(unsigned short)f2bf(val[1])) << 16);
      unsigned int p1 = ((unsigned int)(unsigned short)f2bf(val[2])) |
                        (((unsigned int)(unsigned short)f2bf(val[3])) << 16);
      *(unsigned int*)&xs[b][c][r][2 + col4 * 4]     = p0;
      *(unsigned int*)&xs[b][c][r][2 + col4 * 4 + 2] = p1;
    }
    __syncthreads();

    float acc[2][16];
    #pragma unroll
    for (int oo = 0; oo < 2; ++oo)
      #pragma unroll
      for (int b = 0; b < 16; ++b) acc[oo][b] = 0.f;

    #pragma unroll 1
    for (int c = 0; c < C_; ++c) {
      #pragma unroll 1
      for (int kh = 0; kh < KS; ++kh) {
        float wA[KS], wB[KS];
        const float* wpA = lcw + ((long)o0 * PSZ + c * 25 + kh * 5) * 1024 + h * 32 + w;
        const float* wpB = wpA + (long)PSZ * 1024;
        #pragma unroll
        for (int p = 0; p < KS; ++p) {
          wA[p] = wpA[(long)p * 1024];
          wB[p] = wpB[(long)p * 1024];
        }
        #pragma unroll
        for (int b = 0; b < 16; ++b) {
          const unsigned int* rowp = (const unsigned int*)&xs[b][c][kh][0];
          unsigned int d0 = rowp[w];       // stored cols 2w,2w+1   (kw 0,1)
          unsigned int d1 = rowp[w + 1];   // stored cols 2w+2,2w+3 (kw 2,3)
          unsigned int d2 = rowp[w + 2];   // stored col  2w+4      (kw 4)
          float v0 = u2f(d0 << 16), v1 = u2f(d0 & 0xffff0000u);
          float v2 = u2f(d1 << 16), v3 = u2f(d1 & 0xffff0000u);
          float v4 = u2f(d2 << 16);
          acc[0][b] += wA[0] * v0 + wA[1] * v1 + wA[2] * v2 + wA[3] * v3 + wA[4] * v4;
          acc[1][b] += wB[0] * v0 + wB[1] * v1 + wB[2] * v2 + wB[3] * v3 + wB[4] * v4;
        }
      }
    }

    #pragma unroll
    for (int oo = 0; oo < 2; ++oo)
      #pragma unroll
      for (int b = 0; b < 16; ++b)
        outb[((long)(bg * 16 + b) * OC + (o0 + oo)) * 1024 + h * 32 + w] =
            (unsigned short)f2bf(acc[oo][b]);
  }
}

// ---------------- K2: BN1 batch stats -> scale/shift per channel ------------
__global__ __launch_bounds__(1024) void k2_stats(
    const unsigned short* __restrict__ outb,
    const float* __restrict__ g, const float* __restrict__ bta,
    float* __restrict__ sc, float* __restrict__ sh) {
  const int o = blockIdx.x;
  const int tid = threadIdx.x;
  float s = 0.f, s2 = 0.f;
  const int i8 = (tid & 127) * 8;
  const int bsub = tid >> 7;
  for (int pass = 0; pass < 16; ++pass) {
    int b = bsub + pass * 8;
    const short8 v = *(const short8*)(outb + (((long)b * OC + o) << 10) + i8);
    #pragma unroll
    for (int j = 0; j < 8; ++j) { float f = bf2f(v[j]); s += f; s2 += f * f; }
  }
  #pragma unroll
  for (int off = 32; off; off >>= 1) {
    s  += __shfl_down(s, off);
    s2 += __shfl_down(s2, off);
  }
  __shared__ float ls[16], ls2[16];
  int wid = tid >> 6;
  if ((tid & 63) == 0) { ls[wid] = s; ls2[wid] = s2; }
  __syncthreads();
  if (tid == 0) {
    float ts = 0.f, ts2 = 0.f;
    for (int i = 0; i < 16; ++i) { ts += ls[i]; ts2 += ls2[i]; }
    const float inv = 1.0f / (float)(B_ * 1024);
    float mean = ts * inv;
    float var  = ts2 * inv - mean * mean;
    float rstd = 1.0f / sqrtf(var + EPSV);
    float scv  = g[o] * rstd;
    sc[o] = scv;
    sh[o] = bta[o] - mean * scv;
  }
}

// ---------------- K2.5: BN1+ReLU -> SWIZZLED packed bf16 activations --------
// Chunk layout (16B units): chunk c = kb*512 + mf*64 + lq*16 + l15
//   holds A[m = mf*16+l15][k = kb*32 + lq*8 .. +7]
__global__ __launch_bounds__(256) void k25_pack(
    const unsigned short* __restrict__ outb,
    const float* __restrict__ sc, const float* __restrict__ sh,
    unsigned short* __restrict__ ab) {
  const int c = blockIdx.x * 256 + threadIdx.x;   // chunk id, 2048*512 total
  const int l15 = c & 15;
  const int lq  = (c >> 4) & 3;
  const int mf  = (c >> 6) & 7;
  const int kb  = c >> 9;
  const int m   = mf * 16 + l15;
  const int k   = kb * 32 + lq * 8;
  const int o   = k >> 10;
  const int hw  = k & 1023;
  float scv = sc[o], shv = sh[o];
  short8 v = *(const short8*)(outb + ((long)m * 64 + o) * 1024 + hw);
  short8 r;
  #pragma unroll
  for (int j = 0; j < 8; ++j) {
    float f = bf2f(v[j]) * scv + shv;
    r[j] = f2bf(fmaxf(f, 0.f));
  }
  *(short8*)(ab + (long)c * 8) = r;
}

// ---------------- K3: FC1 GEMM — counted-vmcnt depth-2 DMA pipeline ---------
// (REVERT to the R6/R7-validated structure, ~117us: 3 buf x 16KB = 48KB LDS,
// 3 blocks/CU, vmcnt(4), per-block k-phase rotation, XCD swizzle, setprio.
// Depth-4 and k=64 supersteps both measured neutral-or-worse; the ~3.7 TB/s
// W-stream efficiency is the current ceiling.)
__global__ __launch_bounds__(256, 3) void k3_gemm(
    const unsigned short* __restrict__ ab, const float* __restrict__ w1,
    float* __restrict__ part, int ksteps, int splits) {
  // bijective XCD swizzle: physical dispatch id -> logical block
  const int nwg = 24 * splits;
  const int chunk = nwg >> 3;                 // nwg % 8 == 0
  const int bid = blockIdx.x;
  const int lid = (bid & 7) * chunk + (bid >> 3);
  const int split = lid / 24;
  const int ntile = lid % 24;

  const int tid  = threadIdx.x;
  const int lane = tid & 63;
  const int wid  = tid >> 6;
  const int n0   = ntile * 64 + wid * 16;
  const int l15  = lane & 15;
  const int lq   = lane >> 4;

  __shared__ unsigned short sa[3][4096];   // A: 3 x 8KB
  __shared__ float sw[3][4][512];          // W: 3 x 8KB (per-wave 2KB slots)

  const int kb0 = split * ksteps;
  const int kmask = ksteps - 1;               // ksteps is pow2
  const int phase = (lid * 29) & kmask;       // per-block k-rotation
  const long wsrc = (long)(n0 + l15) * FCIN + (long)kb0 * 32 + lq * 8;
  const int last = ksteps - 1;

#define STAGE(T, BUF) do {                                                   \
    int Tp = ((T) + phase) & kmask;                                          \
    long gb = ((long)(kb0 + Tp) * 512 + wid * 128) * 8;                      \
    unsigned short* lb = &sa[BUF][wid * 1024];                               \
    gld16(ab + gb + (long)lane * 8, lb);                                     \
    gld16(ab + gb + 512 + (long)lane * 8, lb + 512);                         \
    const float* wg = w1 + wsrc + (long)Tp * 32;                             \
    float* wlb = &sw[BUF][wid][0];                                           \
    gld16f(wg, wlb);                                                         \
    gld16f(wg + 4, wlb + 256);                                               \
  } while (0)

#define COMPUTE(X) do {                                                      \
    f32x4 wv0 = *(const f32x4*)&sw[X][wid][lane * 4];                        \
    f32x4 wv1 = *(const f32x4*)&sw[X][wid][256 + lane * 4];                  \
    bf16x8 bfr;                                                              \
    _Pragma("unroll")                                                        \
    for (int j = 0; j < 4; ++j) bfr[j] = f2bf(wv0[j]);                       \
    _Pragma("unroll")                                                        \
    for (int j = 0; j < 4; ++j) bfr[4 + j] = f2bf(wv1[j]);                   \
    __builtin_amdgcn_s_setprio(1);                                           \
    _Pragma("unroll")                                                        \
    for (int m = 0; m < 8; ++m) {                                            \
      bf16x8 afr = *(const bf16x8*)(&sa[X][m * 512 + lane * 8]);             \
      acc[m] = __builtin_amdgcn_mfma_f32_16x16x32_bf16(afr, bfr, acc[m], 0, 0, 0); \
    }                                                                        \
    __builtin_amdgcn_s_setprio(0);                                           \
  } while (0)

  f32x4 acc[8];
  #pragma unroll
  for (int m = 0; m < 8; ++m) acc[m] = (f32x4){0.f, 0.f, 0.f, 0.f};

  STAGE(0, 0);
  STAGE((1 <= last ? 1 : last), 1);

  for (int t = 0; t < ksteps; ++t) {
    asm volatile("s_waitcnt vmcnt(4)" ::: "memory");   // stage(t) landed; stage(t+1) stays in flight
    __builtin_amdgcn_sched_barrier(0);
    __builtin_amdgcn_s_barrier();
    __builtin_amdgcn_sched_barrier(0);
    int tn = (t + 2 <= last) ? (t + 2) : last;         // clamped dummy keeps DMA count uniform
    STAGE(tn, (t + 2) % 3);
    COMPUTE(t % 3);
  }
#undef STAGE
#undef COMPUTE

  float* pp = part + (long)split * (B_ * HID);
  #pragma unroll
  for (int m = 0; m < 8; ++m) {
    int row = m * 16 + lq * 4;
    #pragma unroll
    for (int r = 0; r < 4; ++r)
      pp[(long)(row + r) * HID + n0 + l15] = acc[m][r];
  }
}

// ---------------- K4: reduce split-K + BN2 + ReLU -> h2 fp32 ----------------
__global__ __launch_bounds__(256) void k4_bn2(
    const float* __restrict__ part, const float* __restrict__ g2,
    const float* __restrict__ b2, float* __restrict__ h2, int splits) {
  const int nb = blockIdx.x;
  const int tid = threadIdx.x;
  const int nl = tid & 3;
  const int bt = tid >> 2;          // 0..63
  const int n  = nb * 4 + nl;

  float h0 = 0.f, h1 = 0.f;
  for (int s = 0; s < splits; ++s) {
    const float* pp = part + (long)s * (B_ * HID) + n;
    h0 += pp[(long)bt * HID];
    h1 += pp[(long)(bt + 64) * HID];
  }
  float s1 = h0 + h1, s2v = h0 * h0 + h1 * h1;

  __shared__ float r1[256], r2[256];
  r1[tid] = s1; r2[tid] = s2v;
  __syncthreads();
  for (int off = 32; off; off >>= 1) {
    if (bt < off) { r1[tid] += r1[tid + off * 4]; r2[tid] += r2[tid + off * 4]; }
    __syncthreads();
  }
  __shared__ float scs[4], shs[4];
  if (bt == 0) {
    float mean = r1[nl] * (1.0f / 128.f);
    float var  = r2[nl] * (1.0f / 128.f) - mean * mean;
    float rstd = 1.0f / sqrtf(var + EPSV);
    float sc = g2[n] * rstd;
    scs[nl] = sc; shs[nl] = b2[n] - mean * sc;
  }
  __syncthreads();
  float sc = scs[nl], shf = shs[nl];
  h2[(long)bt * HID + n]        = fmaxf(h0 * sc + shf, 0.f);
  h2[(long)(bt + 64) * HID + n] = fmaxf(h1 * sc + shf, 0.f);
}

// ---------------- K5: FC2 -> out [128,10] -----------------------------------
__global__ __launch_bounds__(256) void k5_fc2(
    const float* __restrict__ h2, const float* __restrict__ w2,
    float* __restrict__ out) {
  const int b = blockIdx.x;
  const int tid = threadIdx.x;
  float acc[NCLS];
  #pragma unroll
  for (int c = 0; c < NCLS; ++c) acc[c] = 0.f;
  for (int n = tid; n < HID; n += 256) {
    float hvv = h2[(long)b * HID + n];
    #pragma unroll
    for (int c = 0; c < NCLS; ++c) acc[c] += hvv * w2[c * HID + n];
  }
  #pragma unroll
  for (int off = 32; off; off >>= 1)
    #pragma unroll
    for (int c = 0; c < NCLS; ++c) acc[c] += __shfl_down(acc[c], off);
  __shared__ float ls[4][NCLS];
  int wid = tid >> 6;
  if ((tid & 63) == 0)
    for (int c = 0; c < NCLS; ++c) ls[wid][c] = acc[c];
  __syncthreads();
  if (tid < NCLS)
    out[b * NCLS + tid] = ls[0][tid] + ls[1][tid] + ls[2][tid] + ls[3][tid];
}

extern "C" void kernel_launch(void* const* d_in, const int* in_sizes, int n_in,
                              void* d_out, int out_size, void* d_ws, size_t ws_size,
                              hipStream_t stream) {
  const float* x    = (const float*)d_in[0];
  const float* lcw  = (const float*)d_in[1];
  const float* bn1g = (const float*)d_in[2];
  const float* bn1b = (const float*)d_in[3];
  const float* fc1w = (const float*)d_in[4];
  const float* bn2g = (const float*)d_in[5];
  const float* bn2b = (const float*)d_in[6];
  const float* fc2w = (const float*)d_in[7];
  float* out = (float*)d_out;

  char* ws = (char*)d_ws;
  unsigned short* outb = (unsigned short*)(ws);                              // 16 MiB
  unsigned short* ab   = (unsigned short*)(ws + (size_t)16 * 1024 * 1024);   // 16 MiB
  float* sc1 = (float*)(ws + (size_t)32 * 1024 * 1024);
  float* sh1 = sc1 + 64;
  size_t base = (size_t)32 * 1024 * 1024 + 4096;
  float* part = (float*)(ws + base);

  int splits = 32;                       // auto-degrade if ws too small
  size_t h2need = (size_t)B_ * HID * 4;
  while (splits > 4 && base + (size_t)splits * B_ * HID * 4 + h2need > ws_size)
    splits >>= 1;
  float* h2 = (float*)(ws + base + (size_t)splits * B_ * HID * 4);

  k1_conv<<<dim3(32, 4, 4), 256, 0, stream>>>(x, lcw, outb);
  k2_stats<<<64, 1024, 0, stream>>>(outb, bn1g, bn1b, sc1, sh1);
  k25_pack<<<4096, 256, 0, stream>>>(outb, sc1, sh1, ab);
  int ksteps = FCIN / splits / 32;
  k3_gemm<<<24 * splits, 256, 0, stream>>>(ab, fc1w, part, ksteps, splits);
  k4_bn2<<<384, 256, 0, stream>>>(part, bn2g, bn2b, h2, splits);
  k5_fc2<<<128, 256, 0, stream>>>(h2, fc2w, out);
}